// Round 1
// baseline (416.985 us; speedup 1.0000x reference)
//
#include <hip/hip_runtime.h>

#define T_ 15
#define CIN 6
#define H0 160
#define W0 160
#define C1_ 128
#define C2_ 256
#define HP 83            // padded pooled grid (83x83)
#define H2 82            // conv2 output (82x82)
#define NPIX (H0*W0)     // 25600
#define NIN (CIN*NPIX)   // 153600
#define NPOS (H2*H2)     // 6724
#define NS (T_*C2_*NPOS) // 25,820,160 elements per s/v output
#define THR1 10.0f
#define THR2 1.0f
#define CG 8             // conv1 output channels per block iteration group

// ---------------------------------------------------------------------------
// K0: recover per-input first-fire time tf = 15 - sum_t inp[t]  (exact: inp is 0/1)
// tf == 15 means "never fires within the window"
__global__ __launch_bounds__(256) void k0_tf(const float* __restrict__ inp,
                                             unsigned char* __restrict__ tf) {
    int i = blockIdx.x * 256 + threadIdx.x;
    if (i >= NIN) return;
    float c = 0.f;
#pragma unroll
    for (int t = 0; t < T_; t++) c += inp[(size_t)t * NIN + i];
    tf[i] = (unsigned char)(15 - (int)(c + 0.5f));
}

// ---------------------------------------------------------------------------
// K1: conv1 (VALID on pad-2 input) -> first t with v1 >= 10, per (c,y,x).
// Bucket trick: each tap contributes w to time-bucket tf; v1[t] = prefix sum.
// LDS buckets d[16][256]: lane column => bank = tid%32, conflict-free.
__global__ __launch_bounds__(256) void k1_conv1(const unsigned char* __restrict__ tfin,
                                                const float* __restrict__ w1,
                                                unsigned char* __restrict__ fst1) {
    __shared__ unsigned char tft[CIN * 20 * 20]; // 2400 B tile of tf
    __shared__ float dbuk[16 * 256];             // 16 KB buckets

    int tid = threadIdx.x;
    int tileId = blockIdx.x;                 // 0..99 (10x10 tiles of 16x16)
    int ty0 = (tileId / 10) * 16, tx0 = (tileId % 10) * 16;

    // load tf tile (window = tile + 2-halo each side; OOB = pad => tf 15)
    for (int i = tid; i < CIN * 400; i += 256) {
        int ci = i / 400, rem = i % 400;
        int ly = rem / 20, lx = rem % 20;
        int y = ty0 + ly - 2, x = tx0 + lx - 2;
        tft[i] = (y >= 0 && y < H0 && x >= 0 && x < W0)
                     ? tfin[ci * NPIX + y * W0 + x] : (unsigned char)15;
    }
    __syncthreads();

    // pack this thread's 150 tap fire-times, 4 bits each, into 19 regs
    int tyl = tid >> 4, txl = tid & 15;
    unsigned int pk[19];
#pragma unroll
    for (int u = 0; u < 19; u++) pk[u] = 0u;
#pragma unroll
    for (int j = 0; j < 150; j++) {
        int ci = j / 25, r = j % 25;
        int ky = r / 5, kx = r % 5;
        unsigned int tfv = tft[ci * 400 + (tyl + ky) * 20 + (txl + kx)];
        pk[j >> 3] |= tfv << ((j & 7) * 4);
    }

    float* col = dbuk + tid;
    int cbase = blockIdx.y * CG;
    for (int cc = 0; cc < CG; cc++) {
        int c = cbase + cc;
#pragma unroll
        for (int tau = 0; tau < 16; tau++) col[tau * 256] = 0.0f;

        const float* wr = w1 + c * 150; // uniform address -> scalar loads
#pragma unroll
        for (int j = 0; j < 150; j++) {
            float w = wr[j];
            unsigned int tfv = (pk[j >> 3] >> ((j & 7) * 4)) & 15u;
            col[tfv * 256] += w; // per-thread private column: no races, no barrier
        }

        float v = 0.f;
        int fst = 15;
#pragma unroll
        for (int tau = 0; tau < 15; tau++) {
            v += col[tau * 256];
            fst = (fst == 15 && v >= THR1) ? tau : fst;
        }
        fst1[c * NPIX + (ty0 + tyl) * W0 + (tx0 + txl)] = (unsigned char)fst;
    }
}

// ---------------------------------------------------------------------------
// K2: maxpool(2,2,pad1) on spikes == min over window of fst1; then pointwise
// inhibition on binary spikes == (min over channels, lowest-index tie) winner.
// Output on padded 83x83 grid; border / never-fired => t=15.
__global__ __launch_bounds__(256) void k2_pool(const unsigned char* __restrict__ fst1,
                                               unsigned char* __restrict__ win_t,
                                               unsigned char* __restrict__ win_ch) {
    int i = blockIdx.x * 256 + threadIdx.x;
    if (i >= HP * HP) return;
    int py = i / HP, px = i % HP;
    if (py == 0 || py == HP - 1 || px == 0 || px == HP - 1) {
        win_t[i] = 15; win_ch[i] = 0; return;
    }
    int y0 = 2 * (py - 1) - 1, x0 = 2 * (px - 1) - 1;
    int best = 15, bc = 0;
    for (int c = 0; c < C1_; c++) {
        const unsigned char* base = fst1 + c * NPIX;
        int m = 15;
#pragma unroll
        for (int dy = 0; dy < 2; dy++) {
            int y = y0 + dy;
            if (y < 0 || y >= H0) continue;
#pragma unroll
            for (int dx = 0; dx < 2; dx++) {
                int x = x0 + dx;
                if (x < 0 || x >= W0) continue;
                int f = base[y * W0 + x];
                m = f < m ? f : m;
            }
        }
        if (m < best) { best = m; bc = c; } // strict < keeps lowest channel on tie
    }
    win_t[i] = (unsigned char)best;
    win_ch[i] = (unsigned char)bc;
}

// ---------------------------------------------------------------------------
// K3: conv2 (4 live taps) + fire(1.0) + pointwise inhibition over 256 channels
// (exact reference formulas) + scatter nonzero s/v + per-position k-WTA prep.
// One block per output position, thread = output channel.
__global__ __launch_bounds__(256) void k3_conv2(const unsigned char* __restrict__ win_t,
                                                const unsigned char* __restrict__ win_ch,
                                                const float* __restrict__ w2,
                                                float* __restrict__ s_out,
                                                float* __restrict__ v_out,
                                                float* __restrict__ vals,
                                                int* __restrict__ nsp_arr,
                                                int* __restrict__ ow_arr,
                                                unsigned int* __restrict__ bigbits) {
    __shared__ unsigned int ormask;
    __shared__ unsigned long long amax;
    int p = blockIdx.x;
    int y2 = p / H2, x2 = p % H2;
    int o = threadIdx.x;
    if (o == 0) { ormask = 0u; amax = 0ull; }
    __syncthreads();

    float w[4]; int tj[4];
#pragma unroll
    for (int k = 0; k < 4; k++) {
        int dy = k >> 1, dx = k & 1;
        int pi = (y2 + dy) * HP + (x2 + dx);
        int tt = win_t[pi];
        int cc = win_ch[pi];
        tj[k] = tt;
        w[k] = (tt < 15) ? w2[(o * C1_ + cc) * 4 + k] : 0.0f;
    }

    float z[T_];
    unsigned int m = 0u;
#pragma unroll
    for (int t = 0; t < T_; t++) {
        float v = 0.f;
#pragma unroll
        for (int k = 0; k < 4; k++) v += (t >= tj[k]) ? w[k] : 0.f;
        float zz = (v < THR2) ? 0.f : v;
        z[t] = zz;
        m |= (zz > 0.f) ? (1u << t) : 0u;
    }

    // block OR of spike masks (wave butterfly then 4 LDS atomics)
    unsigned int mw = m;
#pragma unroll
    for (int off = 32; off > 0; off >>= 1) mw |= __shfl_xor(mw, off);
    if ((o & 63) == 0) atomicOr(&ormask, mw);
    __syncthreads();

    unsigned int om = ormask;
    int count = __popc(om & 0x7FFFu);
    int earliest = 15 - count;
    earliest = earliest < 0 ? 0 : (earliest > 14 ? 14 : earliest);
    int alive = (om >> 14) & 1;

    float zval = 0.f; // z[earliest] via static select (avoid scratch)
#pragma unroll
    for (int t = 0; t < T_; t++) zval = (t == earliest) ? z[t] : zval;

    // argmax over channels, lowest index wins ties
    unsigned long long key =
        ((unsigned long long)__float_as_uint(zval) << 16) | (unsigned long long)(1023 - o);
#pragma unroll
    for (int off = 32; off > 0; off >>= 1) {
        unsigned long long other = __shfl_xor(key, off);
        key = other > key ? other : key;
    }
    if ((o & 63) == 0) atomicMax(&amax, key);
    __syncthreads();

    if (alive) {
        int wo = 1023 - (int)(amax & 0xFFFFull);
        if (o == wo) {
            int nsp = __popc(m & 0x7FFFu);
            int e2 = 15 - nsp;
            e2 = e2 < 0 ? 0 : (e2 > 14 ? 14 : e2);
            float vv = 0.f;
#pragma unroll
            for (int t = 0; t < T_; t++) vv = (t == e2) ? z[t] : vv;
            vals[p] = vv; nsp_arr[p] = nsp; ow_arr[p] = wo;
            if (nsp > 0) atomicMax(bigbits, __float_as_uint(vv)); // vv >= 0
#pragma unroll
            for (int t = 0; t < T_; t++) {
                if (z[t] != 0.f) {
                    int idx = ((t * C2_ + wo) * H2 + y2) * H2 + x2;
                    v_out[idx] = z[t];
                    s_out[idx] = 1.0f;
                }
            }
        }
    } else if (o == 0) {
        vals[p] = 0.f; nsp_arr[p] = 0; ow_arr[p] = 0;
    }
}

// ---------------------------------------------------------------------------
// K4: greedy k-WTA (8 winners), exact reference tie-break (flat index
// f*NPOS + r*82 + col, first occurrence) and kill rule (whole channel OR
// Chebyshev radius 1). Single block.
__global__ __launch_bounds__(1024) void k4_kwta(const float* __restrict__ vals,
                                                const int* __restrict__ nsp,
                                                const int* __restrict__ ow,
                                                const unsigned int* __restrict__ bigbits,
                                                float* __restrict__ wout) {
    __shared__ float tot[NPOS];
    __shared__ short och[NPOS];
    __shared__ unsigned long long amax;
    int tid = threadIdx.x;
    float big = __uint_as_float(*bigbits) * 15.0f;

    for (int p = tid; p < NPOS; p += 1024) {
        int n = nsp[p];
        tot[p] = (n > 0) ? (float)n * (vals[p] + big) : 0.0f;
        och[p] = (short)ow[p];
    }
    if (tid == 0) amax = 0ull;
    __syncthreads();

    for (int it = 0; it < 8; it++) {
        unsigned long long best = 0ull;
        for (int p = tid; p < NPOS; p += 1024) {
            float tv = tot[p];
            if (tv > 0.0f) {
                unsigned int k = (unsigned)och[p] * (unsigned)NPOS + (unsigned)p; // < 2^21
                unsigned long long pk =
                    ((unsigned long long)__float_as_uint(tv) << 21) |
                    (unsigned long long)(0x1FFFFFu - k);
                best = pk > best ? pk : best;
            }
        }
#pragma unroll
        for (int off = 32; off > 0; off >>= 1) {
            unsigned long long other = __shfl_xor(best, off);
            best = other > best ? other : best;
        }
        if ((tid & 63) == 0) atomicMax(&amax, best);
        __syncthreads();
        unsigned long long mx = amax;
        __syncthreads();
        if (tid == 0) amax = 0ull;

        if (mx == 0ull) {
            if (tid == 0) {
                wout[it * 3 + 0] = -1.f; wout[it * 3 + 1] = -1.f; wout[it * 3 + 2] = -1.f;
            }
        } else {
            unsigned int k = 0x1FFFFFu - (unsigned)(mx & 0x1FFFFFull);
            int f = (int)(k / NPOS), pp = (int)(k % NPOS);
            int r = pp / H2, col = pp % H2;
            if (tid == 0) {
                wout[it * 3 + 0] = (float)f; wout[it * 3 + 1] = (float)r; wout[it * 3 + 2] = (float)col;
            }
            for (int p = tid; p < NPOS; p += 1024) {
                int pr = p / H2, pc = p % H2;
                bool kill = (och[p] == (short)f) ||
                            (pr >= r - 1 && pr <= r + 1 && pc >= col - 1 && pc <= col + 1);
                if (kill) tot[p] = 0.0f;
            }
        }
        __syncthreads();
    }
}

// ---------------------------------------------------------------------------
extern "C" void kernel_launch(void* const* d_in, const int* in_sizes, int n_in,
                              void* d_out, int out_size, void* d_ws, size_t ws_size,
                              hipStream_t stream) {
    const float* inp = (const float*)d_in[0];
    const float* w1  = (const float*)d_in[1];
    const float* w2  = (const float*)d_in[2];
    // d_in[3] = layer_idx (always 2) -- deepest branch implemented

    float* out = (float*)d_out;
    float* s_out = out;                    // [15,256,82,82]
    float* v_out = out + (size_t)NS;       // [15,256,82,82]
    float* wnr   = out + 2 * (size_t)NS;   // [8,3] as floats

    // Big scratch lives in the v-region of d_out (consumed before the memset).
    unsigned char* tfin = (unsigned char*)d_out + (size_t)NS * sizeof(float);
    unsigned char* fst1 = tfin + (1u << 20);

    // Small scratch in d_ws (~115 KB used).
    unsigned char* win_t  = (unsigned char*)d_ws;            // 6889 B
    unsigned char* win_ch = (unsigned char*)d_ws + 8192;     // 6889 B
    float* vals = (float*)((char*)d_ws + 16384);             // 26.9 KB
    int*   nsp  = (int*)((char*)d_ws + 49152);               // 26.9 KB
    int*   ow   = (int*)((char*)d_ws + 81920);               // 26.9 KB
    unsigned int* bigbits = (unsigned int*)((char*)d_ws + 114688);

    hipLaunchKernelGGL(k0_tf, dim3(NIN / 256), dim3(256), 0, stream, inp, tfin);
    hipLaunchKernelGGL(k1_conv1, dim3(100, C1_ / CG), dim3(256), 0, stream, tfin, w1, fst1);
    hipLaunchKernelGGL(k2_pool, dim3((HP * HP + 255) / 256), dim3(256), 0, stream,
                       fst1, win_t, win_ch);

    // zero outputs (scratch in d_out is dead past this point)
    hipMemsetAsync(d_out, 0, (size_t)out_size * sizeof(float), stream);
    hipMemsetAsync(bigbits, 0, sizeof(unsigned int), stream);

    hipLaunchKernelGGL(k3_conv2, dim3(NPOS), dim3(256), 0, stream,
                       win_t, win_ch, w2, s_out, v_out, vals, nsp, ow, bigbits);
    hipLaunchKernelGGL(k4_kwta, dim3(1), dim3(1024), 0, stream, vals, nsp, ow, bigbits, wnr);
}

// Round 2
// 282.762 us; speedup vs baseline: 1.4747x; 1.4747x over previous
//
#include <hip/hip_runtime.h>

#define T_ 15
#define CIN 6
#define H0 160
#define W0 160
#define C1_ 128
#define C2_ 256
#define HP 83            // padded pooled grid (83x83)
#define H2 82            // conv2 output (82x82)
#define NPIX (H0*W0)     // 25600
#define NIN (CIN*NPIX)   // 153600
#define NPOS (H2*H2)     // 6724
#define NS (T_*C2_*NPOS) // 25,820,160 elements per s/v output
#define THR1 10.0f
#define THR2 1.0f
#define CG 8             // conv1 output channels per block iteration group

// ---------------------------------------------------------------------------
// K0: recover per-input first-fire time tf = 15 - sum_t inp[t]  (exact: inp is 0/1)
__global__ __launch_bounds__(256) void k0_tf(const float* __restrict__ inp,
                                             unsigned char* __restrict__ tf) {
    int i = blockIdx.x * 256 + threadIdx.x;
    if (i >= NIN) return;
    float c = 0.f;
#pragma unroll
    for (int t = 0; t < T_; t++) c += inp[(size_t)t * NIN + i];
    tf[i] = (unsigned char)(15 - (int)(c + 0.5f));
}

// ---------------------------------------------------------------------------
// K1: conv1 -> first t with v1 >= 10 per (c,y,x) via 16-slot time-bucket
// histogram in LDS. v2: two channels per bucket slot (float2, ds_*_b64) --
// halves LDS instruction count per channel-tap (LDS pipe is the bottleneck).
__global__ __launch_bounds__(256) void k1_conv1(const unsigned char* __restrict__ tfin,
                                                const float* __restrict__ w1,
                                                unsigned char* __restrict__ fst1) {
    __shared__ unsigned char tft[CIN * 20 * 20]; // 2400 B tile of tf
    __shared__ float dbuk[16 * 512];             // 32 KB: [tau][tid][2ch]

    int tid = threadIdx.x;
    int tileId = blockIdx.x;                 // 0..99 (10x10 tiles of 16x16)
    int ty0 = (tileId / 10) * 16, tx0 = (tileId % 10) * 16;

    for (int i = tid; i < CIN * 400; i += 256) {
        int ci = i / 400, rem = i % 400;
        int ly = rem / 20, lx = rem % 20;
        int y = ty0 + ly - 2, x = tx0 + lx - 2;
        tft[i] = (y >= 0 && y < H0 && x >= 0 && x < W0)
                     ? tfin[ci * NPIX + y * W0 + x] : (unsigned char)15;
    }
    __syncthreads();

    // pack this thread's 150 tap fire-times, 4 bits each, into 19 regs
    int tyl = tid >> 4, txl = tid & 15;
    unsigned int pk[19];
#pragma unroll
    for (int u = 0; u < 19; u++) pk[u] = 0u;
#pragma unroll
    for (int j = 0; j < 150; j++) {
        int ci = j / 25, r = j % 25;
        int ky = r / 5, kx = r % 5;
        unsigned int tfv = tft[ci * 400 + (tyl + ky) * 20 + (txl + kx)];
        pk[j >> 3] |= tfv << ((j & 7) * 4);
    }

    float* col = dbuk + 2 * tid; // this thread's float2 column
    int cbase = blockIdx.y * CG;
    int pix = (ty0 + tyl) * W0 + (tx0 + txl);

    for (int cc = 0; cc < CG; cc += 2) {
        const float* wr0 = w1 + (cbase + cc) * 150;     // uniform -> scalar loads
        const float* wr1 = wr0 + 150;
#pragma unroll
        for (int tau = 0; tau < 16; tau++)
            *(float2*)(col + tau * 512) = make_float2(0.f, 0.f);

#pragma unroll
        for (int j = 0; j < 150; j++) {
            unsigned int tfv = (pk[j >> 3] >> ((j & 7) * 4)) & 15u;
            float2* slot = (float2*)(col + tfv * 512);  // private column: no races
            float2 v = *slot;
            v.x += wr0[j];
            v.y += wr1[j];
            *slot = v;
        }

        float v0 = 0.f, v1 = 0.f;
        int f0 = 15, f1 = 15;
#pragma unroll
        for (int tau = 0; tau < 15; tau++) {
            float2 bv = *(float2*)(col + tau * 512);
            v0 += bv.x; v1 += bv.y;
            f0 = (f0 == 15 && v0 >= THR1) ? tau : f0;
            f1 = (f1 == 15 && v1 >= THR1) ? tau : f1;
        }
        fst1[(cbase + cc) * NPIX + pix] = (unsigned char)f0;
        fst1[(cbase + cc + 1) * NPIX + pix] = (unsigned char)f1;
    }
}

// ---------------------------------------------------------------------------
// K2 v2: one 128-thread block per padded-grid position; thread = channel.
// pool-min over 2x2 window, then winner = (min time, lowest channel).
__global__ __launch_bounds__(128) void k2_pool(const unsigned char* __restrict__ fst1,
                                               unsigned char* __restrict__ win_t,
                                               unsigned char* __restrict__ win_ch) {
    __shared__ int wmin[2];
    int i = blockIdx.x;
    int c = threadIdx.x;
    int py = i / HP, px = i % HP;
    if (py == 0 || py == HP - 1 || px == 0 || px == HP - 1) {
        if (c == 0) { win_t[i] = 15; win_ch[i] = 0; }
        return;
    }
    int y0 = 2 * py - 3, x0 = 2 * px - 3;
    const unsigned char* base = fst1 + c * NPIX;
    int m = 15;
#pragma unroll
    for (int dy = 0; dy < 2; dy++) {
        int y = y0 + dy;
        if ((unsigned)y < (unsigned)H0) {
#pragma unroll
            for (int dx = 0; dx < 2; dx++) {
                int x = x0 + dx;
                if ((unsigned)x < (unsigned)W0) {
                    int f = base[y * W0 + x];
                    m = f < m ? f : m;
                }
            }
        }
    }
    int key = (m << 8) | c;
#pragma unroll
    for (int off = 32; off > 0; off >>= 1) {
        int other = __shfl_xor(key, off);
        key = other < key ? other : key;
    }
    if ((c & 63) == 0) wmin[c >> 6] = key;
    __syncthreads();
    if (c == 0) {
        int k = wmin[0] < wmin[1] ? wmin[0] : wmin[1];
        win_t[i] = (unsigned char)(k >> 8);
        win_ch[i] = (unsigned char)(k & 255);
    }
}

// ---------------------------------------------------------------------------
// K3: conv2 (4 live taps) + fire(1.0) + pointwise inhibition over 256 channels
// + scatter nonzero s/v + per-position k-WTA prep. Block = position, thread = channel.
__global__ __launch_bounds__(256) void k3_conv2(const unsigned char* __restrict__ win_t,
                                                const unsigned char* __restrict__ win_ch,
                                                const float* __restrict__ w2,
                                                float* __restrict__ s_out,
                                                float* __restrict__ v_out,
                                                float* __restrict__ vals,
                                                int* __restrict__ nsp_arr,
                                                int* __restrict__ ow_arr,
                                                unsigned int* __restrict__ bigbits) {
    __shared__ unsigned int ormask;
    __shared__ unsigned long long amax;
    int p = blockIdx.x;
    int y2 = p / H2, x2 = p % H2;
    int o = threadIdx.x;
    if (o == 0) { ormask = 0u; amax = 0ull; }
    __syncthreads();

    float w[4]; int tj[4];
#pragma unroll
    for (int k = 0; k < 4; k++) {
        int dy = k >> 1, dx = k & 1;
        int pi = (y2 + dy) * HP + (x2 + dx);
        int tt = win_t[pi];
        int cc = win_ch[pi];
        tj[k] = tt;
        w[k] = (tt < 15) ? w2[(o * C1_ + cc) * 4 + k] : 0.0f;
    }

    float z[T_];
    unsigned int m = 0u;
#pragma unroll
    for (int t = 0; t < T_; t++) {
        float v = 0.f;
#pragma unroll
        for (int k = 0; k < 4; k++) v += (t >= tj[k]) ? w[k] : 0.f;
        float zz = (v < THR2) ? 0.f : v;
        z[t] = zz;
        m |= (zz > 0.f) ? (1u << t) : 0u;
    }

    unsigned int mw = m;
#pragma unroll
    for (int off = 32; off > 0; off >>= 1) mw |= __shfl_xor(mw, off);
    if ((o & 63) == 0) atomicOr(&ormask, mw);
    __syncthreads();

    unsigned int om = ormask;
    int count = __popc(om & 0x7FFFu);
    int earliest = 15 - count;
    earliest = earliest < 0 ? 0 : (earliest > 14 ? 14 : earliest);
    int alive = (om >> 14) & 1;

    float zval = 0.f;
#pragma unroll
    for (int t = 0; t < T_; t++) zval = (t == earliest) ? z[t] : zval;

    unsigned long long key =
        ((unsigned long long)__float_as_uint(zval) << 16) | (unsigned long long)(1023 - o);
#pragma unroll
    for (int off = 32; off > 0; off >>= 1) {
        unsigned long long other = __shfl_xor(key, off);
        key = other > key ? other : key;
    }
    if ((o & 63) == 0) atomicMax(&amax, key);
    __syncthreads();

    if (alive) {
        int wo = 1023 - (int)(amax & 0xFFFFull);
        if (o == wo) {
            int nsp = __popc(m & 0x7FFFu);
            int e2 = 15 - nsp;
            e2 = e2 < 0 ? 0 : (e2 > 14 ? 14 : e2);
            float vv = 0.f;
#pragma unroll
            for (int t = 0; t < T_; t++) vv = (t == e2) ? z[t] : vv;
            vals[p] = vv; nsp_arr[p] = nsp; ow_arr[p] = wo;
            if (nsp > 0) atomicMax(bigbits, __float_as_uint(vv));
#pragma unroll
            for (int t = 0; t < T_; t++) {
                if (z[t] != 0.f) {
                    int idx = ((t * C2_ + wo) * H2 + y2) * H2 + x2;
                    v_out[idx] = z[t];
                    s_out[idx] = 1.0f;
                }
            }
        }
    } else if (o == 0) {
        vals[p] = 0.f; nsp_arr[p] = 0; ow_arr[p] = 0;
    }
}

// ---------------------------------------------------------------------------
// K4: greedy k-WTA (8 winners), exact reference tie-break and kill rule.
__global__ __launch_bounds__(1024) void k4_kwta(const float* __restrict__ vals,
                                                const int* __restrict__ nsp,
                                                const int* __restrict__ ow,
                                                const unsigned int* __restrict__ bigbits,
                                                float* __restrict__ wout) {
    __shared__ float tot[NPOS];
    __shared__ short och[NPOS];
    __shared__ unsigned long long amax;
    int tid = threadIdx.x;
    float big = __uint_as_float(*bigbits) * 15.0f;

    for (int p = tid; p < NPOS; p += 1024) {
        int n = nsp[p];
        tot[p] = (n > 0) ? (float)n * (vals[p] + big) : 0.0f;
        och[p] = (short)ow[p];
    }
    if (tid == 0) amax = 0ull;
    __syncthreads();

    for (int it = 0; it < 8; it++) {
        unsigned long long best = 0ull;
        for (int p = tid; p < NPOS; p += 1024) {
            float tv = tot[p];
            if (tv > 0.0f) {
                unsigned int k = (unsigned)och[p] * (unsigned)NPOS + (unsigned)p;
                unsigned long long pk =
                    ((unsigned long long)__float_as_uint(tv) << 21) |
                    (unsigned long long)(0x1FFFFFu - k);
                best = pk > best ? pk : best;
            }
        }
#pragma unroll
        for (int off = 32; off > 0; off >>= 1) {
            unsigned long long other = __shfl_xor(best, off);
            best = other > best ? other : best;
        }
        if ((tid & 63) == 0) atomicMax(&amax, best);
        __syncthreads();
        unsigned long long mx = amax;
        __syncthreads();
        if (tid == 0) amax = 0ull;

        if (mx == 0ull) {
            if (tid == 0) {
                wout[it * 3 + 0] = -1.f; wout[it * 3 + 1] = -1.f; wout[it * 3 + 2] = -1.f;
            }
        } else {
            unsigned int k = 0x1FFFFFu - (unsigned)(mx & 0x1FFFFFull);
            int f = (int)(k / NPOS), pp = (int)(k % NPOS);
            int r = pp / H2, col = pp % H2;
            if (tid == 0) {
                wout[it * 3 + 0] = (float)f; wout[it * 3 + 1] = (float)r; wout[it * 3 + 2] = (float)col;
            }
            for (int p = tid; p < NPOS; p += 1024) {
                int pr = p / H2, pc = p % H2;
                bool kill = (och[p] == (short)f) ||
                            (pr >= r - 1 && pr <= r + 1 && pc >= col - 1 && pc <= col + 1);
                if (kill) tot[p] = 0.0f;
            }
        }
        __syncthreads();
    }
}

// ---------------------------------------------------------------------------
extern "C" void kernel_launch(void* const* d_in, const int* in_sizes, int n_in,
                              void* d_out, int out_size, void* d_ws, size_t ws_size,
                              hipStream_t stream) {
    const float* inp = (const float*)d_in[0];
    const float* w1  = (const float*)d_in[1];
    const float* w2  = (const float*)d_in[2];

    float* out = (float*)d_out;
    float* s_out = out;                    // [15,256,82,82]
    float* v_out = out + (size_t)NS;       // [15,256,82,82]
    float* wnr   = out + 2 * (size_t)NS;   // [8,3] as floats

    // Big scratch lives in the v-region of d_out (consumed before the memset).
    unsigned char* tfin = (unsigned char*)d_out + (size_t)NS * sizeof(float);
    unsigned char* fst1 = tfin + (1u << 20);

    unsigned char* win_t  = (unsigned char*)d_ws;            // 6889 B
    unsigned char* win_ch = (unsigned char*)d_ws + 8192;     // 6889 B
    float* vals = (float*)((char*)d_ws + 16384);
    int*   nsp  = (int*)((char*)d_ws + 49152);
    int*   ow   = (int*)((char*)d_ws + 81920);
    unsigned int* bigbits = (unsigned int*)((char*)d_ws + 114688);

    hipLaunchKernelGGL(k0_tf, dim3(NIN / 256), dim3(256), 0, stream, inp, tfin);
    hipLaunchKernelGGL(k1_conv1, dim3(100, C1_ / CG), dim3(256), 0, stream, tfin, w1, fst1);
    hipLaunchKernelGGL(k2_pool, dim3(HP * HP), dim3(128), 0, stream, fst1, win_t, win_ch);

    hipMemsetAsync(d_out, 0, (size_t)out_size * sizeof(float), stream);
    hipMemsetAsync(bigbits, 0, sizeof(unsigned int), stream);

    hipLaunchKernelGGL(k3_conv2, dim3(NPOS), dim3(256), 0, stream,
                       win_t, win_ch, w2, s_out, v_out, vals, nsp, ow, bigbits);
    hipLaunchKernelGGL(k4_kwta, dim3(1), dim3(1024), 0, stream, vals, nsp, ow, bigbits, wnr);
}

// Round 3
// 215.738 us; speedup vs baseline: 1.9328x; 1.3107x over previous
//
#include <hip/hip_runtime.h>

#define T_ 15
#define CIN 6
#define H0 160
#define W0 160
#define C1_ 128
#define C2_ 256
#define HP 83            // padded pooled grid (83x83)
#define H2 82            // conv2 output (82x82)
#define NPIX (H0*W0)     // 25600
#define NIN (CIN*NPIX)   // 153600
#define NPOS (H2*H2)     // 6724
#define NS (T_*C2_*NPOS) // 25,820,160 elements per s/v output
#define THR1 10.0f
#define THR2 1.0f

// ---------------------------------------------------------------------------
// K0: (a) tf = 15 - sum_t inp[t] (exact, inp is 0/1); (b) transpose w1 to
// wT[j][c] so lane=channel weight loads are coalesced float2.
__global__ __launch_bounds__(256) void k0_tf(const float* __restrict__ inp,
                                             const float* __restrict__ w1,
                                             unsigned char* __restrict__ tf,
                                             float* __restrict__ wT) {
    int b = blockIdx.x;
    if (b < NIN / 256) {
        int i = b * 256 + threadIdx.x;
        float c = 0.f;
#pragma unroll
        for (int t = 0; t < T_; t++) c += inp[(size_t)t * NIN + i];
        tf[i] = (unsigned char)(15 - (int)(c + 0.5f));
    } else {
        int idx = (b - NIN / 256) * 256 + threadIdx.x;
        if (idx < 150 * C1_) {
            int j = idx >> 7, c = idx & 127;
            wT[idx] = w1[c * 150 + j];
        }
    }
}

// ---------------------------------------------------------------------------
// K0b: per-pixel stable counting sort of the 150 conv1 taps by fire time.
// Outputs: perm[pix][160] (u8 tap indices, actives only, tf-major j-minor) and
// cum[pix][16] (u8 inclusive counts per t). lane = pixel; counts live in
// per-lane LDS columns (bank = tid%32, conflict-free; no syncthreads needed).
__global__ __launch_bounds__(256) void k0b_sort(const unsigned char* __restrict__ tfin,
                                                unsigned char* __restrict__ perm,
                                                unsigned char* __restrict__ cumb) {
    __shared__ int cnt[16 * 256];
    int tid = threadIdx.x;
    int ty0 = (blockIdx.x / 10) * 16, tx0 = (blockIdx.x % 10) * 16;
    int tyl = tid >> 4, txl = tid & 15;
    int y = ty0 + tyl, x = tx0 + txl;
    int pix = y * W0 + x;

    // pack 150 tap fire-times, 4 bits each (OOB/pad => 15 => excluded)
    unsigned int pk[19];
#pragma unroll
    for (int u = 0; u < 19; u++) pk[u] = 0u;
#pragma unroll
    for (int j = 0; j < 150; j++) {
        int ci = j / 25, r = j % 25, ky = r / 5, kx = r % 5;
        int yy = y + ky - 2, xx = x + kx - 2;
        unsigned int tfv = ((unsigned)yy < (unsigned)H0 && (unsigned)xx < (unsigned)W0)
                               ? (unsigned)tfin[ci * NPIX + yy * W0 + xx] : 15u;
        pk[j >> 3] |= tfv << ((j & 7) * 4);
    }

    int* col = cnt + tid;
#pragma unroll
    for (int t = 0; t < 16; t++) col[t * 256] = 0;
#pragma unroll
    for (int j = 0; j < 150; j++) {
        unsigned int tfv = (pk[j >> 3] >> ((j & 7) * 4)) & 15u;
        col[tfv * 256]++;
    }

    int c[15];
#pragma unroll
    for (int t = 0; t < 15; t++) c[t] = col[t * 256];

    // inclusive cum bytes (cum[t] = #taps with tf<=t), packed into uint4
    unsigned int w0 = 0, wA = 0, wB = 0, wC = 0;
    int acc = 0;
#pragma unroll
    for (int t = 0; t < 15; t++) {
        acc += c[t];
        if (t < 4)       w0 |= (unsigned)acc << (8 * t);
        else if (t < 8)  wA |= (unsigned)acc << (8 * (t - 4));
        else if (t < 12) wB |= (unsigned)acc << (8 * (t - 8));
        else             wC |= (unsigned)acc << (8 * (t - 12));
    }
    *(uint4*)(cumb + (size_t)pix * 16) = make_uint4(w0, wA, wB, wC);

    // exclusive starts back into LDS, then stable place pass
    int s = 0;
#pragma unroll
    for (int t = 0; t < 15; t++) { col[t * 256] = s; s += c[t]; }

    unsigned char* pr = perm + (size_t)pix * 160;
#pragma unroll
    for (int j = 0; j < 150; j++) {
        unsigned int tfv = (pk[j >> 3] >> ((j & 7) * 4)) & 15u;
        if (tfv < 15u) { int pos = col[tfv * 256]++; pr[pos] = (unsigned char)j; }
    }
}

// ---------------------------------------------------------------------------
// K1: wave = one pixel, lane = channel pair (2c,2c+1). Iterate taps in tf
// order; bucket_acc per t then v += bucket_acc reproduces the exact fp32
// summation tree of the previous (passing) kernel. Early-exit when all 128
// channels have crossed THR1 (typically after ~25 of 150 taps). No LDS.
__global__ __launch_bounds__(256) void k1_main(const unsigned char* __restrict__ perm,
                                               const unsigned char* __restrict__ cumb,
                                               const float* __restrict__ wT,
                                               unsigned char* __restrict__ fst1) {
    int wid = blockIdx.x * 4 + (threadIdx.x >> 6);
    int lane = threadIdx.x & 63;
    for (int pix = wid; pix < NPIX; pix += 6400) {
        uint4 cw = *(const uint4*)(cumb + (size_t)pix * 16);
        const unsigned char* pp = perm + (size_t)pix * 160;
        const float* wb = wT + 2 * lane;
        float v0 = 0.f, v1 = 0.f;
        int f0 = 15, f1 = 15, i = 0;

#define K1STEP(TT, CE)                                                          \
        {                                                                       \
            int ce = __builtin_amdgcn_readfirstlane((int)(CE));                 \
            float b0 = 0.f, b1 = 0.f;                                           \
            for (; i < ce; ++i) {                                               \
                int j = pp[i];                                                  \
                float2 w = *(const float2*)(wb + j * C1_);                      \
                b0 += w.x; b1 += w.y;                                           \
            }                                                                   \
            v0 += b0; v1 += b1;                                                 \
            if (f0 == 15 && v0 >= THR1) f0 = TT;                                \
            if (f1 == 15 && v1 >= THR1) f1 = TT;                                \
            if (__all((f0 < 15) & (f1 < 15))) goto done;                        \
        }

        K1STEP(0,  cw.x & 255u)         K1STEP(1,  (cw.x >> 8) & 255u)
        K1STEP(2,  (cw.x >> 16) & 255u) K1STEP(3,  (cw.x >> 24) & 255u)
        K1STEP(4,  cw.y & 255u)         K1STEP(5,  (cw.y >> 8) & 255u)
        K1STEP(6,  (cw.y >> 16) & 255u) K1STEP(7,  (cw.y >> 24) & 255u)
        K1STEP(8,  cw.z & 255u)         K1STEP(9,  (cw.z >> 8) & 255u)
        K1STEP(10, (cw.z >> 16) & 255u) K1STEP(11, (cw.z >> 24) & 255u)
        K1STEP(12, cw.w & 255u)         K1STEP(13, (cw.w >> 8) & 255u)
        K1STEP(14, (cw.w >> 16) & 255u)
#undef K1STEP
done:
        *(uchar2*)(fst1 + (size_t)pix * C1_ + 2 * lane) =
            make_uchar2((unsigned char)f0, (unsigned char)f1);
    }
}

// ---------------------------------------------------------------------------
// K2: wave = one padded-grid position, lane = channel pair. pool-min over the
// 2x2 window of fst1[pix][ch], then winner = min (tf<<8 | ch) across channels.
__global__ __launch_bounds__(256) void k2_pool(const unsigned char* __restrict__ fst1,
                                               unsigned char* __restrict__ win_t,
                                               unsigned char* __restrict__ win_ch) {
    int pos = blockIdx.x * 4 + (threadIdx.x >> 6);
    int lane = threadIdx.x & 63;
    if (pos >= HP * HP) return;
    int py = pos / HP, px = pos % HP;
    if (py == 0 || py == HP - 1 || px == 0 || px == HP - 1) {
        if (lane == 0) { win_t[pos] = 15; win_ch[pos] = 0; }
        return;
    }
    int y0 = 2 * py - 3, x0 = 2 * px - 3;
    int m0 = 15, m1 = 15;
#pragma unroll
    for (int dy = 0; dy < 2; dy++) {
        int y = y0 + dy;
        if ((unsigned)y < (unsigned)H0) {
#pragma unroll
            for (int dx = 0; dx < 2; dx++) {
                int x = x0 + dx;
                if ((unsigned)x < (unsigned)W0) {
                    uchar2 f = *(const uchar2*)(fst1 + (size_t)(y * W0 + x) * C1_ + 2 * lane);
                    m0 = f.x < m0 ? f.x : m0;
                    m1 = f.y < m1 ? f.y : m1;
                }
            }
        }
    }
    int k0 = (m0 << 8) | (2 * lane);
    int k1 = (m1 << 8) | (2 * lane + 1);
    int key = k0 < k1 ? k0 : k1;
#pragma unroll
    for (int off = 32; off > 0; off >>= 1) {
        int other = __shfl_xor(key, off);
        key = other < key ? other : key;
    }
    if (lane == 0) {
        win_t[pos] = (unsigned char)(key >> 8);
        win_ch[pos] = (unsigned char)(key & 255);
    }
}

// ---------------------------------------------------------------------------
// K3: conv2 (4 live taps) + fire(1.0) + pointwise inhibition over 256 channels
// + scatter nonzero s/v + per-position k-WTA prep. Block = position, thread = channel.
__global__ __launch_bounds__(256) void k3_conv2(const unsigned char* __restrict__ win_t,
                                                const unsigned char* __restrict__ win_ch,
                                                const float* __restrict__ w2,
                                                float* __restrict__ s_out,
                                                float* __restrict__ v_out,
                                                float* __restrict__ vals,
                                                int* __restrict__ nsp_arr,
                                                int* __restrict__ ow_arr,
                                                unsigned int* __restrict__ bigbits) {
    __shared__ unsigned int ormask;
    __shared__ unsigned long long amax;
    int p = blockIdx.x;
    int y2 = p / H2, x2 = p % H2;
    int o = threadIdx.x;
    if (o == 0) { ormask = 0u; amax = 0ull; }
    __syncthreads();

    float w[4]; int tj[4];
#pragma unroll
    for (int k = 0; k < 4; k++) {
        int dy = k >> 1, dx = k & 1;
        int pi = (y2 + dy) * HP + (x2 + dx);
        int tt = win_t[pi];
        int cc = win_ch[pi];
        tj[k] = tt;
        w[k] = (tt < 15) ? w2[(o * C1_ + cc) * 4 + k] : 0.0f;
    }

    float z[T_];
    unsigned int m = 0u;
#pragma unroll
    for (int t = 0; t < T_; t++) {
        float v = 0.f;
#pragma unroll
        for (int k = 0; k < 4; k++) v += (t >= tj[k]) ? w[k] : 0.f;
        float zz = (v < THR2) ? 0.f : v;
        z[t] = zz;
        m |= (zz > 0.f) ? (1u << t) : 0u;
    }

    unsigned int mw = m;
#pragma unroll
    for (int off = 32; off > 0; off >>= 1) mw |= __shfl_xor(mw, off);
    if ((o & 63) == 0) atomicOr(&ormask, mw);
    __syncthreads();

    unsigned int om = ormask;
    int count = __popc(om & 0x7FFFu);
    int earliest = 15 - count;
    earliest = earliest < 0 ? 0 : (earliest > 14 ? 14 : earliest);
    int alive = (om >> 14) & 1;

    float zval = 0.f;
#pragma unroll
    for (int t = 0; t < T_; t++) zval = (t == earliest) ? z[t] : zval;

    unsigned long long key =
        ((unsigned long long)__float_as_uint(zval) << 16) | (unsigned long long)(1023 - o);
#pragma unroll
    for (int off = 32; off > 0; off >>= 1) {
        unsigned long long other = __shfl_xor(key, off);
        key = other > key ? other : key;
    }
    if ((o & 63) == 0) atomicMax(&amax, key);
    __syncthreads();

    if (alive) {
        int wo = 1023 - (int)(amax & 0xFFFFull);
        if (o == wo) {
            int nsp = __popc(m & 0x7FFFu);
            int e2 = 15 - nsp;
            e2 = e2 < 0 ? 0 : (e2 > 14 ? 14 : e2);
            float vv = 0.f;
#pragma unroll
            for (int t = 0; t < T_; t++) vv = (t == e2) ? z[t] : vv;
            vals[p] = vv; nsp_arr[p] = nsp; ow_arr[p] = wo;
            if (nsp > 0) atomicMax(bigbits, __float_as_uint(vv));
#pragma unroll
            for (int t = 0; t < T_; t++) {
                if (z[t] != 0.f) {
                    int idx = ((t * C2_ + wo) * H2 + y2) * H2 + x2;
                    v_out[idx] = z[t];
                    s_out[idx] = 1.0f;
                }
            }
        }
    } else if (o == 0) {
        vals[p] = 0.f; nsp_arr[p] = 0; ow_arr[p] = 0;
    }
}

// ---------------------------------------------------------------------------
// K4: greedy k-WTA (8 winners), exact reference tie-break and kill rule.
__global__ __launch_bounds__(1024) void k4_kwta(const float* __restrict__ vals,
                                                const int* __restrict__ nsp,
                                                const int* __restrict__ ow,
                                                const unsigned int* __restrict__ bigbits,
                                                float* __restrict__ wout) {
    __shared__ float tot[NPOS];
    __shared__ short och[NPOS];
    __shared__ unsigned long long amax;
    int tid = threadIdx.x;
    float big = __uint_as_float(*bigbits) * 15.0f;

    for (int p = tid; p < NPOS; p += 1024) {
        int n = nsp[p];
        tot[p] = (n > 0) ? (float)n * (vals[p] + big) : 0.0f;
        och[p] = (short)ow[p];
    }
    if (tid == 0) amax = 0ull;
    __syncthreads();

    for (int it = 0; it < 8; it++) {
        unsigned long long best = 0ull;
        for (int p = tid; p < NPOS; p += 1024) {
            float tv = tot[p];
            if (tv > 0.0f) {
                unsigned int k = (unsigned)och[p] * (unsigned)NPOS + (unsigned)p;
                unsigned long long pk =
                    ((unsigned long long)__float_as_uint(tv) << 21) |
                    (unsigned long long)(0x1FFFFFu - k);
                best = pk > best ? pk : best;
            }
        }
#pragma unroll
        for (int off = 32; off > 0; off >>= 1) {
            unsigned long long other = __shfl_xor(best, off);
            best = other > best ? other : best;
        }
        if ((tid & 63) == 0) atomicMax(&amax, best);
        __syncthreads();
        unsigned long long mx = amax;
        __syncthreads();
        if (tid == 0) amax = 0ull;

        if (mx == 0ull) {
            if (tid == 0) {
                wout[it * 3 + 0] = -1.f; wout[it * 3 + 1] = -1.f; wout[it * 3 + 2] = -1.f;
            }
        } else {
            unsigned int k = 0x1FFFFFu - (unsigned)(mx & 0x1FFFFFull);
            int f = (int)(k / NPOS), pp = (int)(k % NPOS);
            int r = pp / H2, col = pp % H2;
            if (tid == 0) {
                wout[it * 3 + 0] = (float)f; wout[it * 3 + 1] = (float)r; wout[it * 3 + 2] = (float)col;
            }
            for (int p = tid; p < NPOS; p += 1024) {
                int pr = p / H2, pc = p % H2;
                bool kill = (och[p] == (short)f) ||
                            (pr >= r - 1 && pr <= r + 1 && pc >= col - 1 && pc <= col + 1);
                if (kill) tot[p] = 0.0f;
            }
        }
        __syncthreads();
    }
}

// ---------------------------------------------------------------------------
extern "C" void kernel_launch(void* const* d_in, const int* in_sizes, int n_in,
                              void* d_out, int out_size, void* d_ws, size_t ws_size,
                              hipStream_t stream) {
    const float* inp = (const float*)d_in[0];
    const float* w1  = (const float*)d_in[1];
    const float* w2  = (const float*)d_in[2];

    float* out = (float*)d_out;
    float* s_out = out;                    // [15,256,82,82]
    float* v_out = out + (size_t)NS;       // [15,256,82,82]
    float* wnr   = out + 2 * (size_t)NS;   // [8,3] as floats

    // Big scratch lives in the v-region of d_out (consumed before the memset).
    char* scratch = (char*)d_out + (size_t)NS * sizeof(float);
    unsigned char* tfin = (unsigned char*)scratch;                    // 150 KB
    float*         wT   = (float*)(scratch + (256 << 10));            // 76.8 KB [j][c]
    unsigned char* cumb = (unsigned char*)(scratch + (512 << 10));    // 409.6 KB
    unsigned char* perm = (unsigned char*)(scratch + (1 << 20));      // 4.096 MB
    unsigned char* fst1 = (unsigned char*)(scratch + (5 << 20));      // 3.27 MB [pix][c]

    unsigned char* win_t  = (unsigned char*)d_ws;
    unsigned char* win_ch = (unsigned char*)d_ws + 8192;
    float* vals = (float*)((char*)d_ws + 16384);
    int*   nsp  = (int*)((char*)d_ws + 49152);
    int*   ow   = (int*)((char*)d_ws + 81920);
    unsigned int* bigbits = (unsigned int*)((char*)d_ws + 114688);

    hipLaunchKernelGGL(k0_tf, dim3(NIN / 256 + 75), dim3(256), 0, stream, inp, w1, tfin, wT);
    hipLaunchKernelGGL(k0b_sort, dim3(100), dim3(256), 0, stream, tfin, perm, cumb);
    hipLaunchKernelGGL(k1_main, dim3(1600), dim3(256), 0, stream, perm, cumb, wT, fst1);
    hipLaunchKernelGGL(k2_pool, dim3((HP * HP + 3) / 4), dim3(256), 0, stream,
                       fst1, win_t, win_ch);

    hipMemsetAsync(d_out, 0, (size_t)out_size * sizeof(float), stream);
    hipMemsetAsync(bigbits, 0, sizeof(unsigned int), stream);

    hipLaunchKernelGGL(k3_conv2, dim3(NPOS), dim3(256), 0, stream,
                       win_t, win_ch, w2, s_out, v_out, vals, nsp, ow, bigbits);
    hipLaunchKernelGGL(k4_kwta, dim3(1), dim3(1024), 0, stream, vals, nsp, ow, bigbits, wnr);
}